// Round 2
// baseline (1043.215 us; speedup 1.0000x reference)
//
#include <hip/hip_runtime.h>

#define NL 3000
#define NP 15000
#define PLEN 8
#define NE 120000
#define DD 16
#define RU 128
#define TT 3

__device__ __forceinline__ float sigmoidf(float x) { return 1.f / (1.f + __expf(-x)); }
__device__ __forceinline__ float tanh_fast(float x) {
    x = fminf(15.f, fmaxf(-15.f, x));   // avoid inf/inf -> NaN
    float e = __expf(2.f * x);
    return (e - 1.f) / (e + 1.f);
}
__device__ __forceinline__ float seluf(float x) {
    const float scale = 1.0507009873554805f, alpha = 1.6732632423543772f;
    return x > 0.f ? scale * x : scale * alpha * (__expf(x) - 1.f);
}

// ---------------- setup kernels ----------------

// init link_state/path_state for both variants; zero lens & linkid map
__global__ void k_init(const float* __restrict__ cap, const float* __restrict__ traffic,
                       float* __restrict__ ls, float* __restrict__ ps,
                       int* __restrict__ lens, int* __restrict__ lid) {
    int i = blockIdx.x * 256 + threadIdx.x;   // grid covers 2*NP*DD = 480000
    if (i < 2 * NL * DD) {
        int d = i & (DD - 1);
        int l = (i >> 4) % NL;
        ls[i] = (d == 0) ? cap[l] : 0.f;
    }
    if (i < 2 * NP * DD) {
        int d = i & (DD - 1);
        int p = (i >> 4) % NP;
        ps[i] = (d == 0) ? traffic[p] : 0.f;
    }
    if (i < NP) lens[i] = 0;
    if (i < NP * PLEN) lid[i] = 0;
}

// copy mask_param to output; fill mask_inserted with 0.5 (sigmoid(0))
__global__ void k_maskfill(const float4* __restrict__ mp_in, float4* __restrict__ out_mp,
                           float4* __restrict__ out_mi) {
    const int n4 = (NL * NP) / 4;   // 11,250,000
    float4 h;
    h.x = 0.5f; h.y = 0.5f; h.z = 0.5f; h.w = 0.5f;
    for (int i = blockIdx.x * blockDim.x + threadIdx.x; i < n4; i += gridDim.x * blockDim.x) {
        out_mp[i] = mp_in[i];
        out_mi[i] = h;
    }
}

// per-edge: multiplicity count, gathered masks for both variants, scatter-fix
// mask_inserted, subgraph_gathered output, lens, inverse (p,s)->link map
__global__ void k_edges(const int* __restrict__ links, const int* __restrict__ paths,
                        const int* __restrict__ seqs, const float* __restrict__ mp,
                        float* __restrict__ mg, float* __restrict__ out_mi,
                        float* __restrict__ out_sg, int* __restrict__ lens,
                        int* __restrict__ lid) {
    int e = blockIdx.x * 256 + threadIdx.x;
    if (e >= NE) return;
    int l = links[e], p = paths[e], s = seqs[e];
    int base = e & ~7;   // edges of one path are contiguous groups of 8 (paths sorted)
    int cnt = 0;
#pragma unroll
    for (int j = 0; j < 8; ++j)
        cnt += (links[base + j] == l && paths[base + j] == p) ? 1 : 0;
    float mpv = mp[(size_t)l * NP + p];
    float sig = sigmoidf(mpv * (float)cnt);
    mg[e] = (float)cnt;        // variant 0: model (hypergraph mask)
    mg[NE + e] = sig;          // variant 1: subgraph (sigmoid mask)
    out_sg[e] = sig;           // subgraph_gathered output
    out_mi[(size_t)l * NP + p] = sig;   // duplicates write identical value -> benign
    atomicAdd(&lens[p], 1);
    lid[p * PLEN + s] = l;     // inverse map (bijective for these inputs)
}

// ---------------- per-T-iteration kernels ----------------

// h_tild scatter: li[v][p][s][d] = ls[v][links[e]][d] * mg[v][e]; also zero m_agg
__global__ void k_scatter(const int* __restrict__ links, const int* __restrict__ paths,
                          const int* __restrict__ seqs, const float* __restrict__ mg,
                          const float* __restrict__ ls, float* __restrict__ li,
                          float* __restrict__ magg) {
    int i = blockIdx.x * 256 + threadIdx.x;   // exactly 2*NE*DD = 3,840,000
    if (i < 2 * NL * DD) magg[i] = 0.f;
    int d = i & (DD - 1);
    int eg = i >> 4;             // v*NE + e
    int v = eg / NE;
    int e = eg - v * NE;
    int l = links[e], p = paths[e], s = seqs[e];
    li[(((size_t)(v * NP + p)) * PLEN + s) * DD + d] = ls[(v * NL + l) * DD + d] * mg[eg];
}

// path GRU scan over 8 steps; 16 lanes per path; outputs aggregated directly
// into m_agg via atomics (fuses the outs-store + gather + segment_sum)
__global__ void k_path_gru(const float* __restrict__ pk, const float* __restrict__ pr,
                           const float* __restrict__ pb, const int* __restrict__ lens,
                           const int* __restrict__ lid, const float* __restrict__ li,
                           float* __restrict__ ps, float* __restrict__ magg) {
    int t = blockIdx.x * 256 + threadIdx.x;   // exactly 2*NP*DD = 480000
    int j = t & (DD - 1);
    int idx = t >> 4;            // v*NP + p
    int v = idx / NP;
    int pp = idx - v * NP;
    float kz[16], kr[16], kh[16], rz[16], rr[16], rh[16];
#pragma unroll
    for (int k = 0; k < 16; ++k) {
        kz[k] = pk[k * 48 + j];
        kr[k] = pk[k * 48 + 16 + j];
        kh[k] = pk[k * 48 + 32 + j];
        rz[k] = pr[k * 48 + j];
        rr[k] = pr[k * 48 + 16 + j];
        rh[k] = pr[k * 48 + 32 + j];
    }
    float bz = pb[j], br = pb[16 + j], bh = pb[32 + j];
    float h = ps[t];
    int len = lens[pp];
    const float* lirow = li + (size_t)idx * PLEN * DD;
#pragma unroll 1
    for (int s = 0; s < PLEN; ++s) {
        float x = lirow[s * DD + j];
        float gxz = 0.f, gxr = 0.f, gxh = 0.f, ghz = 0.f, ghr = 0.f, ghh = 0.f;
#pragma unroll
        for (int k = 0; k < 16; ++k) {
            float xk = __shfl(x, k, 16);
            float hk = __shfl(h, k, 16);
            gxz = fmaf(xk, kz[k], gxz);
            gxr = fmaf(xk, kr[k], gxr);
            gxh = fmaf(xk, kh[k], gxh);
            ghz = fmaf(hk, rz[k], ghz);
            ghr = fmaf(hk, rr[k], ghr);
            ghh = fmaf(hk, rh[k], ghh);
        }
        float z = sigmoidf(gxz + ghz + bz);
        float r = sigmoidf(gxr + ghr + br);
        float c = tanh_fast(gxh + r * ghh + bh);
        float hn = z * h + (1.f - z) * c;
        if (s < len) {               // valid step: update state, emit output
            h = hn;
            int l = lid[pp * PLEN + s];
            atomicAdd(&magg[(v * NL + l) * DD + j], hn);
        }                             // invalid: state frozen, output 0 (skip add)
    }
    ps[t] = h;
}

// link GRU: one step, x = m_agg, h = link_state
__global__ void k_link_gru(const float* __restrict__ ek, const float* __restrict__ er,
                           const float* __restrict__ eb, const float* __restrict__ magg,
                           float* __restrict__ ls) {
    int t = blockIdx.x * 256 + threadIdx.x;   // exactly 2*NL*DD = 96000
    int j = t & (DD - 1);
    float kz[16], kr[16], kh[16], rz[16], rr[16], rh[16];
#pragma unroll
    for (int k = 0; k < 16; ++k) {
        kz[k] = ek[k * 48 + j];
        kr[k] = ek[k * 48 + 16 + j];
        kh[k] = ek[k * 48 + 32 + j];
        rz[k] = er[k * 48 + j];
        rr[k] = er[k * 48 + 16 + j];
        rh[k] = er[k * 48 + 32 + j];
    }
    float bz = eb[j], br = eb[16 + j], bh = eb[32 + j];
    float x = magg[t];
    float h = ls[t];
    float gxz = 0.f, gxr = 0.f, gxh = 0.f, ghz = 0.f, ghr = 0.f, ghh = 0.f;
#pragma unroll
    for (int k = 0; k < 16; ++k) {
        float xk = __shfl(x, k, 16);
        float hk = __shfl(h, k, 16);
        gxz = fmaf(xk, kz[k], gxz);
        gxr = fmaf(xk, kr[k], gxr);
        gxh = fmaf(xk, kh[k], gxh);
        ghz = fmaf(hk, rz[k], ghz);
        ghr = fmaf(hk, rr[k], ghr);
        ghh = fmaf(hk, rh[k], ghh);
    }
    float z = sigmoidf(gxz + ghz + bz);
    float r = sigmoidf(gxr + ghr + br);
    float c = tanh_fast(gxh + r * ghh + bh);
    ls[t] = z * h + (1.f - z) * c;
}

// ---------------- readout ----------------
// selu(ps@w1+b1) -> selu(@w2+b2) -> @w3+b3 ; PT paths per 256-thread block
#define PT 32
__global__ void k_readout(const float* __restrict__ ps,
                          const float* __restrict__ w1, const float* __restrict__ b1,
                          const float* __restrict__ w2, const float* __restrict__ b2,
                          const float* __restrict__ w3, const float* __restrict__ b3,
                          float* __restrict__ out) {
    __shared__ float h1s[PT][RU];
    __shared__ float rsum[PT];
    int j = threadIdx.x & (RU - 1);
    int half = threadIdx.x >> 7;   // 0/1 -> which 16 paths
    int pbase = blockIdx.x * PT;
    if (threadIdx.x < PT) rsum[threadIdx.x] = 0.f;
    // layer 1
    for (int q = 0; q < PT / 2; ++q) {
        int pl = half * (PT / 2) + q;
        int pg = pbase + pl;
        float acc = b1[j];
        if (pg < 2 * NP) {
            const float* psr = ps + pg * DD;
#pragma unroll
            for (int k = 0; k < DD; ++k) acc = fmaf(psr[k], w1[k * RU + j], acc);
        }
        h1s[pl][j] = seluf(acc);
    }
    __syncthreads();
    // layer 2
    float acc2[PT / 2];
#pragma unroll
    for (int q = 0; q < PT / 2; ++q) acc2[q] = b2[j];
    for (int k = 0; k < RU; ++k) {
        float w = w2[k * RU + j];
#pragma unroll
        for (int q = 0; q < PT / 2; ++q)
            acc2[q] = fmaf(h1s[half * (PT / 2) + q][k], w, acc2[q]);
    }
    // layer 3: per-path reduction over the 128 j's (two waves per path-half)
    float w3j = w3[j];
    for (int q = 0; q < PT / 2; ++q) {
        float val = seluf(acc2[q]) * w3j;
#pragma unroll
        for (int off = 32; off > 0; off >>= 1) val += __shfl_down(val, off);
        if ((threadIdx.x & 63) == 0) atomicAdd(&rsum[half * (PT / 2) + q], val);
    }
    __syncthreads();
    if (threadIdx.x < PT) {
        int pg = pbase + threadIdx.x;
        if (pg < 2 * NP) {
            out[pg] = rsum[threadIdx.x] + b3[0];   // [0,NP)=model, [NP,2NP)=subgraph
        }
    }
}

// ---------------- launch ----------------
extern "C" void kernel_launch(void* const* d_in, const int* in_sizes, int n_in,
                              void* d_out, int out_size, void* d_ws, size_t ws_size,
                              hipStream_t stream) {
    const int* links = (const int*)d_in[0];
    const int* paths = (const int*)d_in[1];
    const int* seqs = (const int*)d_in[2];
    const float* cap = (const float*)d_in[3];
    const float* traffic = (const float*)d_in[4];
    const float* mask_param = (const float*)d_in[5];
    const float* pk = (const float*)d_in[6];
    const float* pr = (const float*)d_in[7];
    const float* pb = (const float*)d_in[8];
    const float* ek = (const float*)d_in[9];
    const float* er = (const float*)d_in[10];
    const float* eb = (const float*)d_in[11];
    const float* w1 = (const float*)d_in[12];
    const float* b1 = (const float*)d_in[13];
    const float* w2 = (const float*)d_in[14];
    const float* b2 = (const float*)d_in[15];
    const float* w3 = (const float*)d_in[16];
    const float* b3 = (const float*)d_in[17];

    float* out = (float*)d_out;
    float* out_mi = out + 2 * NP;                       // mask_inserted [NL*NP]
    float* out_sg = out + 2 * NP + (size_t)NL * NP;     // subgraph_gathered [NE]
    float* out_mp = out_sg + NE;                        // mask_param copy [NL*NP]

    char* w = (char*)d_ws;
    float* mg = (float*)w;   w += (size_t)2 * NE * 4;
    float* ls = (float*)w;   w += (size_t)2 * NL * DD * 4;
    float* ps = (float*)w;   w += (size_t)2 * NP * DD * 4;
    float* li = (float*)w;   w += (size_t)2 * NP * PLEN * DD * 4;
    float* magg = (float*)w; w += (size_t)2 * NL * DD * 4;
    int* lens = (int*)w;     w += (size_t)NP * 4;
    int* lid = (int*)w;      w += (size_t)NP * PLEN * 4;

    k_init<<<1875, 256, 0, stream>>>(cap, traffic, ls, ps, lens, lid);
    k_maskfill<<<2048, 256, 0, stream>>>((const float4*)mask_param, (float4*)out_mp,
                                         (float4*)out_mi);
    k_edges<<<(NE + 255) / 256, 256, 0, stream>>>(links, paths, seqs, mask_param, mg,
                                                  out_mi, out_sg, lens, lid);
    for (int t = 0; t < TT; ++t) {
        k_scatter<<<15000, 256, 0, stream>>>(links, paths, seqs, mg, ls, li, magg);
        k_path_gru<<<1875, 256, 0, stream>>>(pk, pr, pb, lens, lid, li, ps, magg);
        k_link_gru<<<375, 256, 0, stream>>>(ek, er, eb, magg, ls);
    }
    k_readout<<<(2 * NP + PT - 1) / PT, 256, 0, stream>>>(ps, w1, b1, w2, b2, w3, b3, out);
}

// Round 3
// 941.933 us; speedup vs baseline: 1.1075x; 1.1075x over previous
//
#include <hip/hip_runtime.h>

#define NL 3000
#define NP 15000
#define PLEN 8
#define NE 120000
#define DD 16
#define RU 128

__device__ __forceinline__ float sigmoidf(float x) { return 1.f / (1.f + __expf(-x)); }
__device__ __forceinline__ float tanh_fast(float x) {
    x = fminf(15.f, fmaxf(-15.f, x));   // avoid inf/inf -> NaN
    float e = __expf(2.f * x);
    return (e - 1.f) / (e + 1.f);
}
__device__ __forceinline__ float seluf(float x) {
    const float scale = 1.0507009873554805f, alpha = 1.6732632423543772f;
    return x > 0.f ? scale * x : scale * alpha * (__expf(x) - 1.f);
}

// ---------------- kernel 1: bulk fill/copy + state init ----------------
// out_mp = mask_param (copy), out_mi = 0.5 everywhere (sigmoid(0); scatter-fix later),
// ls/ps initialized, magg zeroed.
__global__ void k_fill(const float4* __restrict__ mp_in, float4* __restrict__ out_mp,
                       float4* __restrict__ out_mi, const float* __restrict__ cap,
                       const float* __restrict__ traffic, float* __restrict__ ls,
                       float* __restrict__ ps, float* __restrict__ magg) {
    int tid = blockIdx.x * 256 + threadIdx.x;   // 2048*256 = 524288 threads
    if (tid < 2 * NP * DD) {
        int d = tid & (DD - 1);
        int p = (tid >> 4) % NP;
        ps[tid] = (d == 0) ? traffic[p] : 0.f;
        if (tid < 2 * NL * DD) {
            int l = (tid >> 4) % NL;
            ls[tid] = (d == 0) ? cap[l] : 0.f;
            magg[tid] = 0.f;
        }
    }
    const int n4 = (NL * NP) / 4;   // 11,250,000
    float4 h;
    h.x = 0.5f; h.y = 0.5f; h.z = 0.5f; h.w = 0.5f;
    for (int i = tid; i < n4; i += 2048 * 256) {
        out_mp[i] = mp_in[i];
        out_mi[i] = h;
    }
}

// ---------------- kernel 2: per-path edge setup (race-free, no atomics) --------
// For path p, its edges are the contiguous group [8p, 8p+8). Computes per-edge
// (l,p) multiplicity, gathered masks (both variants), lens, (p,s)->link map,
// subgraph_gathered output, and the scatter-fix of mask_inserted.
__global__ void k_setup(const int* __restrict__ links, const int* __restrict__ paths,
                        const int* __restrict__ seqs, const float* __restrict__ mp,
                        float* __restrict__ mgv, int* __restrict__ lens,
                        int* __restrict__ lid, float* __restrict__ out_sg,
                        float* __restrict__ out_mi) {
    int p = blockIdx.x * 256 + threadIdx.x;
    if (p >= NP) return;
    int l8[PLEN], p8[PLEN], s8[PLEN];
#pragma unroll
    for (int j = 0; j < PLEN; ++j) {
        int e = p * PLEN + j;
        l8[j] = links[e]; p8[j] = paths[e]; s8[j] = seqs[e];
    }
    int len = 0;
#pragma unroll
    for (int j = 0; j < PLEN; ++j) len += (p8[j] == p) ? 1 : 0;
    lens[p] = len;
#pragma unroll
    for (int j = 0; j < PLEN; ++j) {
        int e = p * PLEN + j;
        int l = l8[j], s = s8[j];
        int cnt = 0;
#pragma unroll
        for (int k = 0; k < PLEN; ++k)
            cnt += (l8[k] == l && p8[k] == p8[j]) ? 1 : 0;
        float mpv = mp[(size_t)l * NP + p8[j]];
        float sig = sigmoidf(mpv * (float)cnt);
        out_sg[e] = sig;
        out_mi[(size_t)l * NP + p8[j]] = sig;   // duplicates write identical value
        lid[p * PLEN + s] = l;
        mgv[p * PLEN + s] = (float)cnt;             // variant 0 (model)
        mgv[NP * PLEN + p * PLEN + s] = sig;        // variant 1 (subgraph)
    }
}

// ---------------- kernel 3: path GRU with fused gather + fused aggregation ----
// thread (v,p,j): 16 lanes per path; x gathered on the fly from link_state;
// outputs atomically aggregated into magg (EMIT) for the link update.
template <bool EMIT>
__global__ void k_pgru(const float* __restrict__ pk, const float* __restrict__ pr,
                       const float* __restrict__ pb, const int* __restrict__ lens,
                       const int* __restrict__ lid, const float* __restrict__ mgv,
                       const float* __restrict__ ls, float* __restrict__ ps,
                       float* __restrict__ magg) {
    int t = blockIdx.x * 256 + threadIdx.x;   // exactly 2*NP*DD = 480000
    int j = t & (DD - 1);
    int idx = t >> 4;            // v*NP + p
    int v = idx >= NP ? 1 : 0;
    int pp = idx - v * NP;
    float kz[16], kr[16], kh[16], rz[16], rr[16], rh[16];
#pragma unroll
    for (int k = 0; k < 16; ++k) {
        kz[k] = pk[k * 48 + j];
        kr[k] = pk[k * 48 + 16 + j];
        kh[k] = pk[k * 48 + 32 + j];
        rz[k] = pr[k * 48 + j];
        rr[k] = pr[k * 48 + 16 + j];
        rh[k] = pr[k * 48 + 32 + j];
    }
    float bz = pb[j], br = pb[16 + j], bh = pb[32 + j];
    float h = ps[t];
    int len = lens[pp];
#pragma unroll 1
    for (int s = 0; s < PLEN; ++s) {
        int l = lid[pp * PLEN + s];
        float m = mgv[v * NP * PLEN + pp * PLEN + s];
        float x = ls[(v * NL + l) * DD + j] * m;
        float gxz = 0.f, gxr = 0.f, gxh = 0.f, ghz = 0.f, ghr = 0.f, ghh = 0.f;
#pragma unroll
        for (int k = 0; k < 16; ++k) {
            float xk = __shfl(x, k, 16);
            float hk = __shfl(h, k, 16);
            gxz = fmaf(xk, kz[k], gxz);
            gxr = fmaf(xk, kr[k], gxr);
            gxh = fmaf(xk, kh[k], gxh);
            ghz = fmaf(hk, rz[k], ghz);
            ghr = fmaf(hk, rr[k], ghr);
            ghh = fmaf(hk, rh[k], ghh);
        }
        float z = sigmoidf(gxz + ghz + bz);
        float r = sigmoidf(gxr + ghr + br);
        float c = tanh_fast(gxh + r * ghh + bh);
        float hn = z * h + (1.f - z) * c;
        if (s < len) {               // valid step: update state, emit output
            h = hn;
            if (EMIT) atomicAdd(&magg[(v * NL + l) * DD + j], hn);
        }                             // invalid: state frozen, output 0 (skip)
    }
    ps[t] = h;
}

// ---------------- kernel 4: link GRU (x = magg, h = ls); re-zeroes magg -------
__global__ void k_link(const float* __restrict__ ek, const float* __restrict__ er,
                       const float* __restrict__ eb, float* __restrict__ magg,
                       float* __restrict__ ls) {
    int t = blockIdx.x * 256 + threadIdx.x;   // exactly 2*NL*DD = 96000
    int j = t & (DD - 1);
    float kz[16], kr[16], kh[16], rz[16], rr[16], rh[16];
#pragma unroll
    for (int k = 0; k < 16; ++k) {
        kz[k] = ek[k * 48 + j];
        kr[k] = ek[k * 48 + 16 + j];
        kh[k] = ek[k * 48 + 32 + j];
        rz[k] = er[k * 48 + j];
        rr[k] = er[k * 48 + 16 + j];
        rh[k] = er[k * 48 + 32 + j];
    }
    float bz = eb[j], br = eb[16 + j], bh = eb[32 + j];
    float x = magg[t];
    magg[t] = 0.f;                 // ready for next iteration's atomics
    float h = ls[t];
    float gxz = 0.f, gxr = 0.f, gxh = 0.f, ghz = 0.f, ghr = 0.f, ghh = 0.f;
#pragma unroll
    for (int k = 0; k < 16; ++k) {
        float xk = __shfl(x, k, 16);
        float hk = __shfl(h, k, 16);
        gxz = fmaf(xk, kz[k], gxz);
        gxr = fmaf(xk, kr[k], gxr);
        gxh = fmaf(xk, kh[k], gxh);
        ghz = fmaf(hk, rz[k], ghz);
        ghr = fmaf(hk, rr[k], ghr);
        ghh = fmaf(hk, rh[k], ghh);
    }
    float z = sigmoidf(gxz + ghz + bz);
    float r = sigmoidf(gxr + ghr + br);
    float c = tanh_fast(gxh + r * ghh + bh);
    ls[t] = z * h + (1.f - z) * c;
}

// ---------------- kernel 5: readout MLP 16->128->128->1 ----------------------
#define PT 32
__global__ void k_readout(const float* __restrict__ ps,
                          const float* __restrict__ w1, const float* __restrict__ b1,
                          const float* __restrict__ w2, const float* __restrict__ b2,
                          const float* __restrict__ w3, const float* __restrict__ b3,
                          float* __restrict__ out) {
    __shared__ float h1s[PT][RU];
    __shared__ float rsum[PT];
    int j = threadIdx.x & (RU - 1);
    int half = threadIdx.x >> 7;   // 0/1 -> which 16 paths
    int pbase = blockIdx.x * PT;
    if (threadIdx.x < PT) rsum[threadIdx.x] = 0.f;
    for (int q = 0; q < PT / 2; ++q) {
        int pl = half * (PT / 2) + q;
        int pg = pbase + pl;
        float acc = b1[j];
        if (pg < 2 * NP) {
            const float* psr = ps + pg * DD;
#pragma unroll
            for (int k = 0; k < DD; ++k) acc = fmaf(psr[k], w1[k * RU + j], acc);
        }
        h1s[pl][j] = seluf(acc);
    }
    __syncthreads();
    float acc2[PT / 2];
#pragma unroll
    for (int q = 0; q < PT / 2; ++q) acc2[q] = b2[j];
    for (int k = 0; k < RU; ++k) {
        float w = w2[k * RU + j];
#pragma unroll
        for (int q = 0; q < PT / 2; ++q)
            acc2[q] = fmaf(h1s[half * (PT / 2) + q][k], w, acc2[q]);
    }
    float w3j = w3[j];
    for (int q = 0; q < PT / 2; ++q) {
        float val = seluf(acc2[q]) * w3j;
#pragma unroll
        for (int off = 32; off > 0; off >>= 1) val += __shfl_down(val, off);
        if ((threadIdx.x & 63) == 0) atomicAdd(&rsum[half * (PT / 2) + q], val);
    }
    __syncthreads();
    if (threadIdx.x < PT) {
        int pg = pbase + threadIdx.x;
        if (pg < 2 * NP) out[pg] = rsum[threadIdx.x] + b3[0];
    }
}

// ---------------- launch ----------------
extern "C" void kernel_launch(void* const* d_in, const int* in_sizes, int n_in,
                              void* d_out, int out_size, void* d_ws, size_t ws_size,
                              hipStream_t stream) {
    const int* links = (const int*)d_in[0];
    const int* paths = (const int*)d_in[1];
    const int* seqs = (const int*)d_in[2];
    const float* cap = (const float*)d_in[3];
    const float* traffic = (const float*)d_in[4];
    const float* mask_param = (const float*)d_in[5];
    const float* pk = (const float*)d_in[6];
    const float* pr = (const float*)d_in[7];
    const float* pb = (const float*)d_in[8];
    const float* ek = (const float*)d_in[9];
    const float* er = (const float*)d_in[10];
    const float* eb = (const float*)d_in[11];
    const float* w1 = (const float*)d_in[12];
    const float* b1 = (const float*)d_in[13];
    const float* w2 = (const float*)d_in[14];
    const float* b2 = (const float*)d_in[15];
    const float* w3 = (const float*)d_in[16];
    const float* b3 = (const float*)d_in[17];

    float* out = (float*)d_out;
    float* out_mi = out + 2 * NP;                       // mask_inserted [NL*NP]
    float* out_sg = out_mi + (size_t)NL * NP;           // subgraph_gathered [NE]
    float* out_mp = out_sg + NE;                        // mask_param copy [NL*NP]

    char* w = (char*)d_ws;
    float* mgv = (float*)w;  w += (size_t)2 * NP * PLEN * 4;
    float* ls = (float*)w;   w += (size_t)2 * NL * DD * 4;
    float* ps = (float*)w;   w += (size_t)2 * NP * DD * 4;
    float* magg = (float*)w; w += (size_t)2 * NL * DD * 4;
    int* lens = (int*)w;     w += (size_t)NP * 4;
    int* lid = (int*)w;      w += (size_t)NP * PLEN * 4;

    k_fill<<<2048, 256, 0, stream>>>((const float4*)mask_param, (float4*)out_mp,
                                     (float4*)out_mi, cap, traffic, ls, ps, magg);
    k_setup<<<(NP + 255) / 256, 256, 0, stream>>>(links, paths, seqs, mask_param,
                                                  mgv, lens, lid, out_sg, out_mi);
    // T=3; the 3rd link-GRU is dead (outputs depend only on final path_state)
    k_pgru<true><<<1875, 256, 0, stream>>>(pk, pr, pb, lens, lid, mgv, ls, ps, magg);
    k_link<<<375, 256, 0, stream>>>(ek, er, eb, magg, ls);
    k_pgru<true><<<1875, 256, 0, stream>>>(pk, pr, pb, lens, lid, mgv, ls, ps, magg);
    k_link<<<375, 256, 0, stream>>>(ek, er, eb, magg, ls);
    k_pgru<false><<<1875, 256, 0, stream>>>(pk, pr, pb, lens, lid, mgv, ls, ps, magg);
    k_readout<<<(2 * NP + PT - 1) / PT, 256, 0, stream>>>(ps, w1, b1, w2, b2, w3, b3, out);
}

// Round 4
// 633.346 us; speedup vs baseline: 1.6472x; 1.4872x over previous
//
#include <hip/hip_runtime.h>

#define NL 3000
#define NP 15000
#define PLEN 8
#define NE 120000
#define DD 16
#define RU 128

typedef float f4 __attribute__((ext_vector_type(4)));

__device__ __forceinline__ float sigmoidf(float x) { return 1.f / (1.f + __expf(-x)); }
__device__ __forceinline__ float tanh_fast(float x) {
    x = fminf(15.f, fmaxf(-15.f, x));   // avoid inf/inf -> NaN
    float e = __expf(2.f * x);
    return (e - 1.f) / (e + 1.f);
}
__device__ __forceinline__ float seluf(float x) {
    const float scale = 1.0507009873554805f, alpha = 1.6732632423543772f;
    return x > 0.f ? scale * x : scale * alpha * (__expf(x) - 1.f);
}

// ---------------- kernel 1: init states + glx0 + per-path edge setup ----------
// glx[v][l][c] = (ls[v][l] @ pk)[c]; initially ls = [cap,0,...] -> cap[l]*pk[0][c].
__global__ __launch_bounds__(256) void k_init(
    const int* __restrict__ links, const int* __restrict__ paths,
    const int* __restrict__ seqs, const float* __restrict__ mp,
    const float* __restrict__ cap, const float* __restrict__ traffic,
    const float* __restrict__ pk,
    float* __restrict__ ls, float* __restrict__ ps, float* __restrict__ magg,
    float* __restrict__ glx, float* __restrict__ mgv,
    int* __restrict__ lens, int* __restrict__ lid, float* __restrict__ out_sg) {
    int tid = blockIdx.x * 256 + threadIdx.x;   // grid = 1875*256 = 480000 exact
    {   // ps init: tid covers 2*NP*DD exactly
        int d = tid & (DD - 1);
        int q = tid >> 4;               // v*NP + p
        int p = q >= NP ? q - NP : q;
        ps[tid] = (d == 0) ? traffic[p] : 0.f;
    }
    if (tid < 2 * NL * DD) {
        int d = tid & (DD - 1);
        int l = tid >> 4; l = l >= NL ? l - NL : l;
        ls[tid] = (d == 0) ? cap[l] : 0.f;
        magg[tid] = 0.f;
    }
    if (tid < 2 * NL * 48) {
        int c = tid % 48;
        int l = tid / 48; l = l >= NL ? l - NL : l;
        glx[tid] = cap[l] * pk[c];
    }
    if (tid < NP) {   // per-path setup (race-free: a path's 8 edges are contiguous)
        int p = tid;
        int l8[PLEN], p8[PLEN], s8[PLEN];
#pragma unroll
        for (int j = 0; j < PLEN; ++j) {
            int e = p * PLEN + j;
            l8[j] = links[e]; p8[j] = paths[e]; s8[j] = seqs[e];
        }
        int len = 0;
#pragma unroll
        for (int j = 0; j < PLEN; ++j) len += (p8[j] == p) ? 1 : 0;
        lens[p] = len;
#pragma unroll
        for (int j = 0; j < PLEN; ++j) {
            int e = p * PLEN + j;
            int l = l8[j], s = s8[j];
            int cnt = 0;
#pragma unroll
            for (int k = 0; k < PLEN; ++k)
                cnt += (l8[k] == l && p8[k] == p8[j]) ? 1 : 0;
            float mpv = mp[(size_t)l * NP + p8[j]];
            float sig = sigmoidf(mpv * (float)cnt);
            out_sg[e] = sig;
            lid[p * PLEN + s] = l;
            mgv[p * PLEN + s] = (float)cnt;        // variant 0 (model)
            mgv[NP * PLEN + p * PLEN + s] = sig;   // variant 1 (subgraph)
        }
    }
}

// ---------------- kernel 2: path GRU (gx via precomputed glx) + copy slice ----
// 16 lanes per path; gx = m * glx[l]; gh via 16 h-shuffles; outputs atomically
// aggregated into magg (EMIT). Also streams one third of the mask copy/fill
// (nontemporal: don't pollute L2 holding ls/glx/mgv).
#define CPY_CHUNK 3750000   // (NL*NP/4) / 3 float4s per slice
template <bool EMIT, int SLICE>
__global__ __launch_bounds__(256) void k_pgru(
    const float* __restrict__ pr, const float* __restrict__ pb,
    const int* __restrict__ lens, const int* __restrict__ lid,
    const float* __restrict__ mgv, const float* __restrict__ glx,
    float* __restrict__ ps, float* __restrict__ magg,
    const f4* __restrict__ mp_in, f4* __restrict__ out_mp, f4* __restrict__ out_mi) {
    int tid = blockIdx.x * 256 + threadIdx.x;   // 480000 exact = 2*NP*DD
    int j = tid & (DD - 1);
    int idx = tid >> 4;            // v*NP + p
    int v = idx >= NP ? 1 : 0;
    int pp = idx - v * NP;
    float rz[16], rr[16], rh[16];
#pragma unroll
    for (int k = 0; k < 16; ++k) {
        rz[k] = pr[k * 48 + j];
        rr[k] = pr[k * 48 + 16 + j];
        rh[k] = pr[k * 48 + 32 + j];
    }
    float bz = pb[j], br = pb[16 + j], bh = pb[32 + j];
    float h = ps[tid];
    int len = lens[pp];
    const int* lidp = lid + pp * PLEN;
    const float* mgp = mgv + v * NP * PLEN + pp * PLEN;
#pragma unroll
    for (int s = 0; s < PLEN; ++s) {
        int l = lidp[s];
        float m = mgp[s];
        const float* g = glx + (size_t)(v * NL + l) * 48;
        float gxz = g[j] * m, gxr = g[16 + j] * m, gxh = g[32 + j] * m;
        float ghz = 0.f, ghr = 0.f, ghh = 0.f;
#pragma unroll
        for (int k = 0; k < 16; ++k) {
            float hk = __shfl(h, k, 16);
            ghz = fmaf(hk, rz[k], ghz);
            ghr = fmaf(hk, rr[k], ghr);
            ghh = fmaf(hk, rh[k], ghh);
        }
        float z = sigmoidf(gxz + ghz + bz);
        float r = sigmoidf(gxr + ghr + br);
        float c = tanh_fast(gxh + r * ghh + bh);
        float hn = z * h + (1.f - z) * c;
        if (s < len) {
            h = hn;
            if (EMIT) atomicAdd(&magg[(v * NL + l) * DD + j], hn);
        }
    }
    ps[tid] = h;
    // ---- copy slice: out_mp = mask_param, out_mi = 0.5 (scatter-fixed later) ----
    f4 half;
    half.x = 0.5f; half.y = 0.5f; half.z = 0.5f; half.w = 0.5f;
    for (int i = SLICE * CPY_CHUNK + tid; i < (SLICE + 1) * CPY_CHUNK; i += 480000) {
        f4 val = __builtin_nontemporal_load(&mp_in[i]);
        __builtin_nontemporal_store(val, &out_mp[i]);
        __builtin_nontemporal_store(half, &out_mi[i]);
    }
}

// ---------------- kernel 3: link GRU + glx refresh; re-zeroes magg ------------
__global__ __launch_bounds__(256) void k_link(
    const float* __restrict__ ek, const float* __restrict__ er,
    const float* __restrict__ eb, const float* __restrict__ pk,
    float* __restrict__ magg, float* __restrict__ ls, float* __restrict__ glx) {
    int t = blockIdx.x * 256 + threadIdx.x;   // 96000 exact = 2*NL*DD
    int j = t & (DD - 1);
    float kz[16], kr[16], kh[16], rz[16], rr[16], rh[16];
#pragma unroll
    for (int k = 0; k < 16; ++k) {
        kz[k] = ek[k * 48 + j];
        kr[k] = ek[k * 48 + 16 + j];
        kh[k] = ek[k * 48 + 32 + j];
        rz[k] = er[k * 48 + j];
        rr[k] = er[k * 48 + 16 + j];
        rh[k] = er[k * 48 + 32 + j];
    }
    float bz = eb[j], br = eb[16 + j], bh = eb[32 + j];
    float x = magg[t];
    magg[t] = 0.f;                 // ready for next iteration's atomics
    float h = ls[t];
    float gxz = 0.f, gxr = 0.f, gxh = 0.f, ghz = 0.f, ghr = 0.f, ghh = 0.f;
#pragma unroll
    for (int k = 0; k < 16; ++k) {
        float xk = __shfl(x, k, 16);
        float hk = __shfl(h, k, 16);
        gxz = fmaf(xk, kz[k], gxz);
        gxr = fmaf(xk, kr[k], gxr);
        gxh = fmaf(xk, kh[k], gxh);
        ghz = fmaf(hk, rz[k], ghz);
        ghr = fmaf(hk, rr[k], ghr);
        ghh = fmaf(hk, rh[k], ghh);
    }
    float z = sigmoidf(gxz + ghz + bz);
    float r = sigmoidf(gxr + ghr + br);
    float c = tanh_fast(gxh + r * ghh + bh);
    float hn = z * h + (1.f - z) * c;
    ls[t] = hn;
    // refresh glx row for this link: glx[l][c] = sum_k lsnew[k] * pk[k][c]
    float gz = 0.f, gr2 = 0.f, gh2 = 0.f;
#pragma unroll
    for (int k = 0; k < 16; ++k) {
        float hk = __shfl(hn, k, 16);
        gz = fmaf(hk, pk[k * 48 + j], gz);
        gr2 = fmaf(hk, pk[k * 48 + 16 + j], gr2);
        gh2 = fmaf(hk, pk[k * 48 + 32 + j], gh2);
    }
    size_t l48 = (size_t)(t >> 4) * 48;
    glx[l48 + j] = gz;
    glx[l48 + 16 + j] = gr2;
    glx[l48 + 32 + j] = gh2;
}

// ---------------- kernel 4: readout MLP + mask_inserted scatter-fix -----------
#define PT 32
__global__ __launch_bounds__(256) void k_readout(
    const float* __restrict__ ps,
    const float* __restrict__ w1, const float* __restrict__ b1,
    const float* __restrict__ w2, const float* __restrict__ b2,
    const float* __restrict__ w3, const float* __restrict__ b3,
    float* __restrict__ out,
    const int* __restrict__ links, const int* __restrict__ paths,
    const float* __restrict__ out_sg, float* __restrict__ out_mi) {
    // scatter-fix (runs after all copy slices in stream order)
    int gtid = blockIdx.x * 256 + threadIdx.x;
    if (gtid < NE)
        out_mi[(size_t)links[gtid] * NP + paths[gtid]] = out_sg[gtid];

    __shared__ float h1s[PT][RU];
    __shared__ float rsum[PT];
    int j = threadIdx.x & (RU - 1);
    int half = threadIdx.x >> 7;
    int pbase = blockIdx.x * PT;
    if (threadIdx.x < PT) rsum[threadIdx.x] = 0.f;
    for (int q = 0; q < PT / 2; ++q) {
        int pl = half * (PT / 2) + q;
        int pg = pbase + pl;
        float acc = b1[j];
        if (pg < 2 * NP) {
            const float* psr = ps + pg * DD;
#pragma unroll
            for (int k = 0; k < DD; ++k) acc = fmaf(psr[k], w1[k * RU + j], acc);
        }
        h1s[pl][j] = seluf(acc);
    }
    __syncthreads();
    float acc2[PT / 2];
#pragma unroll
    for (int q = 0; q < PT / 2; ++q) acc2[q] = b2[j];
    for (int k = 0; k < RU; ++k) {
        float w = w2[k * RU + j];
#pragma unroll
        for (int q = 0; q < PT / 2; ++q)
            acc2[q] = fmaf(h1s[half * (PT / 2) + q][k], w, acc2[q]);
    }
    float w3j = w3[j];
    for (int q = 0; q < PT / 2; ++q) {
        float val = seluf(acc2[q]) * w3j;
#pragma unroll
        for (int off = 32; off > 0; off >>= 1) val += __shfl_down(val, off);
        if ((threadIdx.x & 63) == 0) atomicAdd(&rsum[half * (PT / 2) + q], val);
    }
    __syncthreads();
    if (threadIdx.x < PT) {
        int pg = pbase + threadIdx.x;
        if (pg < 2 * NP) out[pg] = rsum[threadIdx.x] + b3[0];
    }
}

// ---------------- launch ----------------
extern "C" void kernel_launch(void* const* d_in, const int* in_sizes, int n_in,
                              void* d_out, int out_size, void* d_ws, size_t ws_size,
                              hipStream_t stream) {
    const int* links = (const int*)d_in[0];
    const int* paths = (const int*)d_in[1];
    const int* seqs = (const int*)d_in[2];
    const float* cap = (const float*)d_in[3];
    const float* traffic = (const float*)d_in[4];
    const float* mask_param = (const float*)d_in[5];
    const float* pk = (const float*)d_in[6];
    const float* pr = (const float*)d_in[7];
    const float* pb = (const float*)d_in[8];
    const float* ek = (const float*)d_in[9];
    const float* er = (const float*)d_in[10];
    const float* eb = (const float*)d_in[11];
    const float* w1 = (const float*)d_in[12];
    const float* b1 = (const float*)d_in[13];
    const float* w2 = (const float*)d_in[14];
    const float* b2 = (const float*)d_in[15];
    const float* w3 = (const float*)d_in[16];
    const float* b3 = (const float*)d_in[17];

    float* out = (float*)d_out;
    float* out_mi = out + 2 * NP;                       // mask_inserted [NL*NP]
    float* out_sg = out_mi + (size_t)NL * NP;           // subgraph_gathered [NE]
    float* out_mp = out_sg + NE;                        // mask_param copy [NL*NP]

    char* w = (char*)d_ws;
    float* mgv = (float*)w;  w += (size_t)2 * NP * PLEN * 4;
    float* ls = (float*)w;   w += (size_t)2 * NL * DD * 4;
    float* ps = (float*)w;   w += (size_t)2 * NP * DD * 4;
    float* magg = (float*)w; w += (size_t)2 * NL * DD * 4;
    float* glx = (float*)w;  w += (size_t)2 * NL * 48 * 4;
    int* lens = (int*)w;     w += (size_t)NP * 4;
    int* lid = (int*)w;      w += (size_t)NP * PLEN * 4;

    k_init<<<1875, 256, 0, stream>>>(links, paths, seqs, mask_param, cap, traffic,
                                     pk, ls, ps, magg, glx, mgv, lens, lid, out_sg);
    k_pgru<true, 0><<<1875, 256, 0, stream>>>(pr, pb, lens, lid, mgv, glx, ps, magg,
                                              (const f4*)mask_param, (f4*)out_mp,
                                              (f4*)out_mi);
    k_link<<<375, 256, 0, stream>>>(ek, er, eb, pk, magg, ls, glx);
    k_pgru<true, 1><<<1875, 256, 0, stream>>>(pr, pb, lens, lid, mgv, glx, ps, magg,
                                              (const f4*)mask_param, (f4*)out_mp,
                                              (f4*)out_mi);
    k_link<<<375, 256, 0, stream>>>(ek, er, eb, pk, magg, ls, glx);
    // 3rd link-GRU is dead (outputs depend only on final path_state)
    k_pgru<false, 2><<<1875, 256, 0, stream>>>(pr, pb, lens, lid, mgv, glx, ps, magg,
                                               (const f4*)mask_param, (f4*)out_mp,
                                               (f4*)out_mi);
    k_readout<<<(2 * NP + PT - 1) / PT, 256, 0, stream>>>(ps, w1, b1, w2, b2, w3, b3,
                                                          out, links, paths, out_sg,
                                                          out_mi);
}

// Round 5
// 614.691 us; speedup vs baseline: 1.6971x; 1.0303x over previous
//
#include <hip/hip_runtime.h>

#define NL 3000
#define NP 15000
#define PLEN 8
#define NE 120000
#define DD 16
#define RU 128

typedef float f4 __attribute__((ext_vector_type(4)));

#define N4 ((NL * NP) / 4)          // 11,250,000 float4s in a 45M-float array
#define CPY_CHUNK (N4 / 3)          // 3,750,000 per slice

__device__ __forceinline__ float sigmoidf(float x) { return 1.f / (1.f + __expf(-x)); }
__device__ __forceinline__ float tanh_fast(float x) {
    x = fminf(15.f, fmaxf(-15.f, x));   // avoid inf/inf -> NaN
    float e = __expf(2.f * x);
    return (e - 1.f) / (e + 1.f);
}
__device__ __forceinline__ float seluf(float x) {
    const float scale = 1.0507009873554805f, alpha = 1.6732632423543772f;
    return x > 0.f ? scale * x : scale * alpha * (__expf(x) - 1.f);
}

// ---------------- path GRU (3 modes) + copy slice -----------------------------
// MODE 0: first iteration. Inline per-path setup (no k_init): lanes 0-7 of each
//         16-lane group load the path's 8 edges, compute (l,p) multiplicity and
//         sigmoid mask via shuffles, stash {lid,m,cap} in LDS (same-wave: no
//         barrier), persist lens/lid/mgv for later iterations, write out_sg.
//         gx = cap[l]*m*pk[0][:] (initial ls = [cap,0..0]); h0 from traffic.
//         Copy slice 0 (out_mp+out_mi). Emits magg atomics.
// MODE 1: mid iteration. gx = m*glx[l]; copy slice 1 (out_mp+out_mi); emits.
// MODE 2: last iteration. gx = m*glx[l]; fills out_mi slice 2 only; no emit
//         (3rd link-GRU is dead). Readout copies out_mp slice 2.
template <int MODE>
__global__ __launch_bounds__(256) void k_pgru(
    const int* __restrict__ links, const int* __restrict__ paths,
    const int* __restrict__ seqs, const float* __restrict__ mp,
    const float* __restrict__ cap, const float* __restrict__ traffic,
    const float* __restrict__ pk, const float* __restrict__ pr,
    const float* __restrict__ pb,
    int* __restrict__ lens, int* __restrict__ lid, float* __restrict__ mgv,
    float* __restrict__ out_sg, const float* __restrict__ glx,
    float* __restrict__ ps, float* __restrict__ magg,
    const f4* __restrict__ mp_in, f4* __restrict__ out_mp, f4* __restrict__ out_mi) {
    int tid = blockIdx.x * 256 + threadIdx.x;   // 480000 exact = 2*NP*DD
    int j = tid & (DD - 1);
    int idx = tid >> 4;            // v*NP + p
    int v = idx >= NP ? 1 : 0;
    int pp = idx - v * NP;
    float rz[16], rr[16], rh[16];
#pragma unroll
    for (int k = 0; k < 16; ++k) {
        rz[k] = pr[k * 48 + j];
        rr[k] = pr[k * 48 + 16 + j];
        rh[k] = pr[k * 48 + 32 + j];
    }
    float bz = pb[j], br = pb[16 + j], bh = pb[32 + j];

    __shared__ int s_lid[16][PLEN];
    __shared__ float s_m[16][PLEN];
    __shared__ float s_cap[16][PLEN];
    int g = threadIdx.x >> 4;
    float h;
    int len;
    float pk0z = 0.f, pk0r = 0.f, pk0h = 0.f;

    if (MODE == 0) {
        pk0z = pk[j]; pk0r = pk[16 + j]; pk0h = pk[32 + j];
        int l_e = 0, p_e = 0, s_e = 0;
        if (j < 8) {
            int e = pp * PLEN + j;
            l_e = links[e]; p_e = paths[e]; s_e = seqs[e];
        }
        int cnt = 0;
        len = 0;
#pragma unroll
        for (int k = 0; k < 8; ++k) {
            int lk = __shfl(l_e, k, 16);
            int pk_ = __shfl(p_e, k, 16);
            cnt += (lk == l_e && pk_ == p_e) ? 1 : 0;
            len += (pk_ == pp) ? 1 : 0;
        }
        if (j < 8) {
            float capl = cap[l_e];
            float mpv = mp[(size_t)l_e * NP + p_e];
            float sig = sigmoidf(mpv * (float)cnt);
            s_lid[g][s_e] = l_e;
            s_m[g][s_e] = v ? sig : (float)cnt;
            s_cap[g][s_e] = capl;
            if (v == 0) {
                out_sg[pp * PLEN + j] = sig;
                lid[pp * PLEN + s_e] = l_e;
                mgv[pp * PLEN + s_e] = (float)cnt;
                mgv[NP * PLEN + pp * PLEN + s_e] = sig;
                if (j == 0) lens[pp] = len;
            }
        }
        h = (j == 0) ? traffic[pp] : 0.f;
    } else {
        h = ps[tid];
        len = lens[pp];
    }

    const int* lidp = lid + pp * PLEN;
    const float* mgp = mgv + v * NP * PLEN + pp * PLEN;
#pragma unroll
    for (int s = 0; s < PLEN; ++s) {
        int l;
        float gxz, gxr, gxh;
        if (MODE == 0) {
            l = s_lid[g][s];
            float a = s_cap[g][s] * s_m[g][s];
            gxz = a * pk0z; gxr = a * pk0r; gxh = a * pk0h;
        } else {
            l = lidp[s];
            float m = mgp[s];
            const float* gl = glx + (size_t)(v * NL + l) * 48;
            gxz = gl[j] * m; gxr = gl[16 + j] * m; gxh = gl[32 + j] * m;
        }
        float ghz = 0.f, ghr = 0.f, ghh = 0.f;
#pragma unroll
        for (int k = 0; k < 16; ++k) {
            float hk = __shfl(h, k, 16);
            ghz = fmaf(hk, rz[k], ghz);
            ghr = fmaf(hk, rr[k], ghr);
            ghh = fmaf(hk, rh[k], ghh);
        }
        float z = sigmoidf(gxz + ghz + bz);
        float r = sigmoidf(gxr + ghr + br);
        float c = tanh_fast(gxh + r * ghh + bh);
        float hn = z * h + (1.f - z) * c;
        if (s < len) {
            h = hn;
            if (MODE != 2) atomicAdd(&magg[(v * NL + l) * DD + j], hn);
        }
    }
    ps[tid] = h;

    // ---- copy slice (nontemporal: keep ls/glx/mgv resident in L2) ----
    f4 half;
    half.x = 0.5f; half.y = 0.5f; half.z = 0.5f; half.w = 0.5f;
    if (MODE < 2) {
        const int lo = MODE * CPY_CHUNK, hi = (MODE + 1) * CPY_CHUNK;
        for (int i = lo + tid; i < hi; i += 480000) {
            f4 val = __builtin_nontemporal_load(&mp_in[i]);
            __builtin_nontemporal_store(val, &out_mp[i]);
            __builtin_nontemporal_store(half, &out_mi[i]);
        }
    } else {   // last third of out_mi only (out_mp third done by k_readout)
        for (int i = 2 * CPY_CHUNK + tid; i < N4; i += 480000) {
            __builtin_nontemporal_store(half, &out_mi[i]);
        }
    }
}

// ---------------- link GRU + glx refresh; re-zeroes magg ----------------------
__global__ __launch_bounds__(256) void k_link(
    const float* __restrict__ ek, const float* __restrict__ er,
    const float* __restrict__ eb, const float* __restrict__ pk,
    float* __restrict__ magg, float* __restrict__ ls, float* __restrict__ glx) {
    int t = blockIdx.x * 256 + threadIdx.x;   // 96000 exact = 2*NL*DD
    int j = t & (DD - 1);
    float kz[16], kr[16], kh[16], rz[16], rr[16], rh[16];
#pragma unroll
    for (int k = 0; k < 16; ++k) {
        kz[k] = ek[k * 48 + j];
        kr[k] = ek[k * 48 + 16 + j];
        kh[k] = ek[k * 48 + 32 + j];
        rz[k] = er[k * 48 + j];
        rr[k] = er[k * 48 + 16 + j];
        rh[k] = er[k * 48 + 32 + j];
    }
    float bz = eb[j], br = eb[16 + j], bh = eb[32 + j];
    float x = magg[t];
    magg[t] = 0.f;                 // ready for next iteration's atomics
    float h = ls[t];
    float gxz = 0.f, gxr = 0.f, gxh = 0.f, ghz = 0.f, ghr = 0.f, ghh = 0.f;
#pragma unroll
    for (int k = 0; k < 16; ++k) {
        float xk = __shfl(x, k, 16);
        float hk = __shfl(h, k, 16);
        gxz = fmaf(xk, kz[k], gxz);
        gxr = fmaf(xk, kr[k], gxr);
        gxh = fmaf(xk, kh[k], gxh);
        ghz = fmaf(hk, rz[k], ghz);
        ghr = fmaf(hk, rr[k], ghr);
        ghh = fmaf(hk, rh[k], ghh);
    }
    float z = sigmoidf(gxz + ghz + bz);
    float r = sigmoidf(gxr + ghr + br);
    float c = tanh_fast(gxh + r * ghh + bh);
    float hn = z * h + (1.f - z) * c;
    ls[t] = hn;
    // refresh glx row: glx[l][c] = sum_k ls_new[k] * pk[k][c]
    float gz = 0.f, gr2 = 0.f, gh2 = 0.f;
#pragma unroll
    for (int k = 0; k < 16; ++k) {
        float hk = __shfl(hn, k, 16);
        gz = fmaf(hk, pk[k * 48 + j], gz);
        gr2 = fmaf(hk, pk[k * 48 + 16 + j], gr2);
        gh2 = fmaf(hk, pk[k * 48 + 32 + j], gh2);
    }
    size_t l48 = (size_t)(t >> 4) * 48;
    glx[l48 + j] = gz;
    glx[l48 + 16 + j] = gr2;
    glx[l48 + 32 + j] = gh2;
}

// ---------------- readout MLP + mask_inserted scatter-fix + out_mp slice ------
#define PT 32
__global__ __launch_bounds__(256) void k_readout(
    const float* __restrict__ ps,
    const float* __restrict__ w1, const float* __restrict__ b1,
    const float* __restrict__ w2, const float* __restrict__ b2,
    const float* __restrict__ w3, const float* __restrict__ b3,
    float* __restrict__ out,
    const int* __restrict__ links, const int* __restrict__ paths,
    const float* __restrict__ out_sg, float* __restrict__ out_mi,
    const f4* __restrict__ mp_in, f4* __restrict__ out_mp) {
    int gtid = blockIdx.x * 256 + threadIdx.x;   // 938*256 = 240128 threads
    // last third of out_mp copy (out_mi slice done by pgru<2>)
    for (int i = 2 * CPY_CHUNK + gtid; i < N4; i += 938 * 256) {
        f4 val = __builtin_nontemporal_load(&mp_in[i]);
        __builtin_nontemporal_store(val, &out_mp[i]);
    }
    // scatter-fix of out_mi (all fill slices are earlier in stream order)
    if (gtid < NE)
        out_mi[(size_t)links[gtid] * NP + paths[gtid]] = out_sg[gtid];

    __shared__ float h1s[PT][RU];
    __shared__ float rsum[PT];
    int j = threadIdx.x & (RU - 1);
    int half = threadIdx.x >> 7;
    int pbase = blockIdx.x * PT;
    if (threadIdx.x < PT) rsum[threadIdx.x] = 0.f;
    for (int q = 0; q < PT / 2; ++q) {
        int pl = half * (PT / 2) + q;
        int pg = pbase + pl;
        float acc = b1[j];
        if (pg < 2 * NP) {
            const float* psr = ps + pg * DD;
#pragma unroll
            for (int k = 0; k < DD; ++k) acc = fmaf(psr[k], w1[k * RU + j], acc);
        }
        h1s[pl][j] = seluf(acc);
    }
    __syncthreads();
    float acc2[PT / 2];
#pragma unroll
    for (int q = 0; q < PT / 2; ++q) acc2[q] = b2[j];
    for (int k = 0; k < RU; ++k) {
        float w = w2[k * RU + j];
#pragma unroll
        for (int q = 0; q < PT / 2; ++q)
            acc2[q] = fmaf(h1s[half * (PT / 2) + q][k], w, acc2[q]);
    }
    float w3j = w3[j];
    for (int q = 0; q < PT / 2; ++q) {
        float val = seluf(acc2[q]) * w3j;
#pragma unroll
        for (int off = 32; off > 0; off >>= 1) val += __shfl_down(val, off);
        if ((threadIdx.x & 63) == 0) atomicAdd(&rsum[half * (PT / 2) + q], val);
    }
    __syncthreads();
    if (threadIdx.x < PT) {
        int pg = pbase + threadIdx.x;
        if (pg < 2 * NP) out[pg] = rsum[threadIdx.x] + b3[0];
    }
}

// ---------------- launch ----------------
extern "C" void kernel_launch(void* const* d_in, const int* in_sizes, int n_in,
                              void* d_out, int out_size, void* d_ws, size_t ws_size,
                              hipStream_t stream) {
    const int* links = (const int*)d_in[0];
    const int* paths = (const int*)d_in[1];
    const int* seqs = (const int*)d_in[2];
    const float* cap = (const float*)d_in[3];
    const float* traffic = (const float*)d_in[4];
    const float* mask_param = (const float*)d_in[5];
    const float* pk = (const float*)d_in[6];
    const float* pr = (const float*)d_in[7];
    const float* pb = (const float*)d_in[8];
    const float* ek = (const float*)d_in[9];
    const float* er = (const float*)d_in[10];
    const float* eb = (const float*)d_in[11];
    const float* w1 = (const float*)d_in[12];
    const float* b1 = (const float*)d_in[13];
    const float* w2 = (const float*)d_in[14];
    const float* b2 = (const float*)d_in[15];
    const float* w3 = (const float*)d_in[16];
    const float* b3 = (const float*)d_in[17];

    float* out = (float*)d_out;
    float* out_mi = out + 2 * NP;                       // mask_inserted [NL*NP]
    float* out_sg = out_mi + (size_t)NL * NP;           // subgraph_gathered [NE]
    float* out_mp = out_sg + NE;                        // mask_param copy [NL*NP]

    char* w = (char*)d_ws;
    float* mgv = (float*)w;  w += (size_t)2 * NP * PLEN * 4;
    float* ls = (float*)w;   w += (size_t)2 * NL * DD * 4;
    float* ps = (float*)w;   w += (size_t)2 * NP * DD * 4;
    float* magg = (float*)w; w += (size_t)2 * NL * DD * 4;
    float* glx = (float*)w;  w += (size_t)2 * NL * 48 * 4;
    int* lens = (int*)w;     w += (size_t)NP * 4;
    int* lid = (int*)w;      w += (size_t)NP * PLEN * 4;

    hipMemsetAsync(magg, 0, (size_t)2 * NL * DD * 4, stream);
    // ls only needed by k_link (h of first link-GRU): init via small memset-free
    // trick is not possible (cap values) — but k_link's h is ls=[cap,0..]; we
    // fold that init into k_link? No: keep it simple, init ls here cheaply.
    // (2*NL*DD floats = 384 KB; one tiny kernel-free approach: memset zeros then
    //  k_link reads cap directly is wrong for later iters. Use a micro-kernel.)
    // -> ls init folded into k_pgru<0>? Not possible (cross-block). Micro memset:
    hipMemsetAsync(ls, 0, (size_t)2 * NL * DD * 4, stream);  // zeros; d==0 slot fixed in k_link via cap? NO —
    // simplest correct: k_link reads ls; first k_link call needs ls=[cap,0..].
    // We patch the d==0 lane inside k_pgru<0>: lanes j<8 with v==0 also write
    // ls[(l)*DD+0]=cap[l] — but races with zero memset ordering are fine since
    // memset completes before k_pgru<0> starts (same stream). Duplicate writes
    // of identical values are benign.
    k_pgru<0><<<1875, 256, 0, stream>>>(links, paths, seqs, mask_param, cap, traffic,
                                        pk, pr, pb, lens, lid, mgv, out_sg, glx,
                                        ps, magg, (const f4*)mask_param,
                                        (f4*)out_mp, (f4*)out_mi);
    // fix ls d==0 slots (cap) before first k_link: tiny kernel inline via lambda
    // not allowed; do it in k_link itself? k_link h-read must see cap at d0.
    // Use a dedicated micro-kernel (6000 threads, ~2us):
    {
        struct LsFix {
            static __global__ void run(const float* __restrict__ cap,
                                       float* __restrict__ ls) {
                int t = blockIdx.x * 256 + threadIdx.x;   // 2*NL = 6000
                if (t < 2 * NL) {
                    int l = t >= NL ? t - NL : t;
                    ls[t * DD] = cap[l];
                }
            }
        };
        LsFix::run<<<24, 256, 0, stream>>>(cap, ls);
    }
    k_link<<<375, 256, 0, stream>>>(ek, er, eb, pk, magg, ls, glx);
    k_pgru<1><<<1875, 256, 0, stream>>>(links, paths, seqs, mask_param, cap, traffic,
                                        pk, pr, pb, lens, lid, mgv, out_sg, glx,
                                        ps, magg, (const f4*)mask_param,
                                        (f4*)out_mp, (f4*)out_mi);
    k_link<<<375, 256, 0, stream>>>(ek, er, eb, pk, magg, ls, glx);
    k_pgru<2><<<1875, 256, 0, stream>>>(links, paths, seqs, mask_param, cap, traffic,
                                        pk, pr, pb, lens, lid, mgv, out_sg, glx,
                                        ps, magg, (const f4*)mask_param,
                                        (f4*)out_mp, (f4*)out_mi);
    k_readout<<<938, 256, 0, stream>>>(ps, w1, b1, w2, b2, w3, b3, out, links, paths,
                                       out_sg, out_mi, (const f4*)mask_param,
                                       (f4*)out_mp);
}